// Round 1
// baseline (489.162 us; speedup 1.0000x reference)
//
#include <hip/hip_runtime.h>

// AdaptiveSoftmax on MI355X — round 1: bf16-MFMA fused GEMM+sumexp.
//
// Decomposition:
//   1. Convert inputs/weights to bf16 in ws (weights pre-scaled by log2e).
//   2. h0 = X@lin0, h1 = X@lin1 via bf16 MFMA GEMM, stored bf16.
//   3. For each of {head, tail0, tail1}: fused GEMM -> s[row] += 2^(logit')
//      (logit' = logit*log2e folded into weights). No online max: logits are
//      bounded (|logit| < ~20), fp32 sum cannot overflow.
//   4. Combine kernel: recompute the single target logit per row via a wave
//      dot product, out[row] = ln2 * sum_g (v'_t - log2(s_g)).
//   5. Loss reduction: out[4096] = mean(-out).

typedef __attribute__((ext_vector_type(8))) short short8;
typedef __attribute__((ext_vector_type(4))) float f32x4;

#define LOG2E 1.4426950408889634f
#define LN2   0.6931471805599453f

__device__ __forceinline__ float b2f(unsigned short u){
    return __uint_as_float(((unsigned int)u) << 16);
}
__device__ __forceinline__ unsigned short f2b(float f){
    unsigned int x = __float_as_uint(f);
    x += 0x7fffu + ((x >> 16) & 1u);
    return (unsigned short)(x >> 16);
}
// dot of 2 bf16 pairs packed in uints
__device__ __forceinline__ float dotu(unsigned int xu, unsigned int wu){
    float a = __uint_as_float(xu << 16) * __uint_as_float(wu << 16);
    float b = __uint_as_float(xu & 0xffff0000u) * __uint_as_float(wu & 0xffff0000u);
    return a + b;
}

// ---------------- conversion kernels ----------------
__global__ void k_convert_scale(const float* __restrict__ in,
                                unsigned short* __restrict__ out,
                                int n4, float scale){
    int stride = gridDim.x * blockDim.x;
    for (int i = blockIdx.x*blockDim.x + threadIdx.x; i < n4; i += stride){
        float4 v = ((const float4*)in)[i];
        ushort4 o;
        o.x = f2b(v.x*scale); o.y = f2b(v.y*scale);
        o.z = f2b(v.z*scale); o.w = f2b(v.w*scale);
        ((ushort4*)out)[i] = o;
    }
}

// in: [1024][C] row-major  ->  out: [C][1024] bf16
__global__ void k_transpose_convert(const float* __restrict__ in,
                                    unsigned short* __restrict__ out,
                                    int C, int n){
    int idx = blockIdx.x*blockDim.x + threadIdx.x;
    if (idx < n){
        int c = idx >> 10, d = idx & 1023;
        out[idx] = f2b(in[d*C + c]);
    }
}

// ---------------- fused GEMM + sum-of-exp2 ----------------
// D[i][j] = dot(A[i,:], B[j,:]) over K; accumulate s_out[i] += sum_j 2^D[i][j].
// Block tile: 64 rows x 64 cols, 2x2 wave grid, 16x16x32 bf16 MFMA.
// LDS tiles XOR-swizzled (group g stored at g^(row&7)) -> 2-way conflicts max.
template<int K>
__global__ __launch_bounds__(256) void k_gemm_sumexp(
    const unsigned short* __restrict__ A,   // [4096][K] bf16
    const unsigned short* __restrict__ B,   // [M][K] bf16 (pre-scaled by log2e)
    float* __restrict__ s_out,              // [4096] fp32, pre-zeroed
    int M, int chunks_per_block)
{
    constexpr int KCH = K / 64;
    static_assert(K % 64 == 0, "K must be multiple of 64");
    __shared__ __align__(16) unsigned short As[64*64];
    __shared__ __align__(16) unsigned short Bs[64*64];

    const int tid  = threadIdx.x;
    const int lane = tid & 63;
    const int w    = tid >> 6;
    const int waveR = w >> 1, waveC = w & 1;
    const int quad  = lane >> 4, l16 = lane & 15;
    const int row0  = blockIdx.x * 64;
    const int nchunk = (M + 63) >> 6;
    const int cb0 = blockIdx.y * chunks_per_block;
    const int cb1 = min(nchunk, cb0 + chunks_per_block);

    float s_loc[8];
    #pragma unroll
    for (int i = 0; i < 8; ++i) s_loc[i] = 0.f;

    auto stageA = [&](int kc){
        #pragma unroll
        for (int it = 0; it < 2; ++it){
            int idx = tid + it*256;
            int r = idx >> 3, g = idx & 7;
            const uint4* src = (const uint4*)(A + (row0 + r)*K + kc*64 + g*8);
            *((uint4*)&As[r*64 + ((g ^ (r & 7)) << 3)]) = *src;
        }
    };
    auto stageB = [&](int cb, int kc){
        #pragma unroll
        for (int it = 0; it < 2; ++it){
            int idx = tid + it*256;
            int r = idx >> 3, g = idx & 7;
            int brow = cb*64 + r;
            uint4 v;
            if (brow < M) v = *(const uint4*)(B + brow*K + kc*64 + g*8);
            else { v.x = 0u; v.y = 0u; v.z = 0u; v.w = 0u; }
            *((uint4*)&Bs[r*64 + ((g ^ (r & 7)) << 3)]) = v;
        }
    };

    short8 a_res[2][2];   // [i][ks], used when K == 64 (A tile resident)
    if (KCH == 1){
        stageA(0);
        __syncthreads();
        #pragma unroll
        for (int i = 0; i < 2; ++i)
        #pragma unroll
        for (int ks = 0; ks < 2; ++ks){
            int r = waveR*32 + i*16 + l16;
            int g = ks*4 + quad;
            a_res[i][ks] = *(const short8*)&As[r*64 + ((g ^ (r & 7)) << 3)];
        }
    }

    for (int cb = cb0; cb < cb1; ++cb){
        f32x4 acc[2][2];
        #pragma unroll
        for (int i = 0; i < 2; ++i)
        #pragma unroll
        for (int j = 0; j < 2; ++j)
            acc[i][j] = (f32x4){0.f, 0.f, 0.f, 0.f};

        for (int kc = 0; kc < KCH; ++kc){
            __syncthreads();                 // prior LDS reads done before restage
            if (KCH > 1) stageA(kc);
            stageB(cb, kc);
            __syncthreads();
            #pragma unroll
            for (int ks = 0; ks < 2; ++ks){
                short8 a[2], b[2];
                #pragma unroll
                for (int i = 0; i < 2; ++i){
                    if (KCH == 1) a[i] = a_res[i][ks];
                    else {
                        int r = waveR*32 + i*16 + l16;
                        int g = ks*4 + quad;
                        a[i] = *(const short8*)&As[r*64 + ((g ^ (r & 7)) << 3)];
                    }
                }
                #pragma unroll
                for (int j = 0; j < 2; ++j){
                    int r = waveC*32 + j*16 + l16;
                    int g = ks*4 + quad;
                    b[j] = *(const short8*)&Bs[r*64 + ((g ^ (r & 7)) << 3)];
                }
                #pragma unroll
                for (int i = 0; i < 2; ++i)
                #pragma unroll
                for (int j = 0; j < 2; ++j)
                    acc[i][j] = __builtin_amdgcn_mfma_f32_16x16x32_bf16(
                        a[i], b[j], acc[i][j], 0, 0, 0);
            }
        }
        // epilogue: s += 2^logit  (rows: quad*4+r (+i*16), cols: l16 (+j*16))
        bool full = ((cb + 1) * 64 <= M);
        if (full){
            #pragma unroll
            for (int i = 0; i < 2; ++i)
            #pragma unroll
            for (int j = 0; j < 2; ++j)
            #pragma unroll
            for (int r = 0; r < 4; ++r)
                s_loc[i*4 + r] += exp2f(acc[i][j][r]);
        } else {
            #pragma unroll
            for (int j = 0; j < 2; ++j){
                int col = cb*64 + waveC*32 + j*16 + l16;
                if (col < M){
                    #pragma unroll
                    for (int i = 0; i < 2; ++i)
                    #pragma unroll
                    for (int r = 0; r < 4; ++r)
                        s_loc[i*4 + r] += exp2f(acc[i][j][r]);
                }
            }
        }
    }

    // reduce across the 16 lanes of each quad (plain sums — no max state)
    #pragma unroll
    for (int k = 0; k < 8; ++k){
        #pragma unroll
        for (int m = 1; m < 16; m <<= 1)
            s_loc[k] += __shfl_xor(s_loc[k], m, 64);
    }
    if (l16 < 8){
        int i = l16 >> 2, r = l16 & 3;
        int row = row0 + waveR*32 + i*16 + quad*4 + r;
        atomicAdd(&s_out[row], s_loc[l16]);
    }
}

// ---------------- plain GEMM (K=1024) storing bf16: h = X @ linT^T ----------
__global__ __launch_bounds__(256) void k_gemm_store(
    const unsigned short* __restrict__ A,   // [4096][1024]
    const unsigned short* __restrict__ B,   // [M][1024]
    unsigned short* __restrict__ C,         // [4096][M]
    int M)
{
    constexpr int K = 1024;
    __shared__ __align__(16) unsigned short As[64*64];
    __shared__ __align__(16) unsigned short Bs[64*64];

    const int tid  = threadIdx.x;
    const int lane = tid & 63;
    const int w    = tid >> 6;
    const int waveR = w >> 1, waveC = w & 1;
    const int quad  = lane >> 4, l16 = lane & 15;
    const int row0  = blockIdx.x * 64;
    const int cb    = blockIdx.y;           // column chunk (M multiple of 64)

    f32x4 acc[2][2];
    #pragma unroll
    for (int i = 0; i < 2; ++i)
    #pragma unroll
    for (int j = 0; j < 2; ++j)
        acc[i][j] = (f32x4){0.f, 0.f, 0.f, 0.f};

    for (int kc = 0; kc < K/64; ++kc){
        __syncthreads();
        #pragma unroll
        for (int it = 0; it < 2; ++it){
            int idx = tid + it*256;
            int r = idx >> 3, g = idx & 7;
            *((uint4*)&As[r*64 + ((g ^ (r & 7)) << 3)]) =
                *(const uint4*)(A + (row0 + r)*K + kc*64 + g*8);
            *((uint4*)&Bs[r*64 + ((g ^ (r & 7)) << 3)]) =
                *(const uint4*)(B + (cb*64 + r)*K + kc*64 + g*8);
        }
        __syncthreads();
        #pragma unroll
        for (int ks = 0; ks < 2; ++ks){
            short8 a[2], b[2];
            #pragma unroll
            for (int i = 0; i < 2; ++i){
                int r = waveR*32 + i*16 + l16;
                int g = ks*4 + quad;
                a[i] = *(const short8*)&As[r*64 + ((g ^ (r & 7)) << 3)];
            }
            #pragma unroll
            for (int j = 0; j < 2; ++j){
                int r = waveC*32 + j*16 + l16;
                int g = ks*4 + quad;
                b[j] = *(const short8*)&Bs[r*64 + ((g ^ (r & 7)) << 3)];
            }
            #pragma unroll
            for (int i = 0; i < 2; ++i)
            #pragma unroll
            for (int j = 0; j < 2; ++j)
                acc[i][j] = __builtin_amdgcn_mfma_f32_16x16x32_bf16(
                    a[i], b[j], acc[i][j], 0, 0, 0);
        }
    }
    #pragma unroll
    for (int i = 0; i < 2; ++i)
    #pragma unroll
    for (int j = 0; j < 2; ++j)
    #pragma unroll
    for (int r = 0; r < 4; ++r){
        int row = row0 + waveR*32 + i*16 + quad*4 + r;
        int col = cb*64 + waveC*32 + j*16 + l16;
        C[row*M + col] = f2b(acc[i][j][r]);
    }
}

// ---------------- combine: target logits + assemble log-probs ---------------
__global__ __launch_bounds__(256) void k_combine(
    const unsigned short* __restrict__ Xb,   // [4096][1024]
    const unsigned short* __restrict__ hWb,  // [2002][1024] (scaled)
    const unsigned short* __restrict__ h0b,  // [4096][256]
    const unsigned short* __restrict__ e0b,  // [8000][256] (scaled)
    const unsigned short* __restrict__ h1b,  // [4096][64]
    const unsigned short* __restrict__ e1b,  // [40257][64] (scaled)
    const float* __restrict__ sH, const float* __restrict__ s0,
    const float* __restrict__ s1,
    const int* __restrict__ targets, float* __restrict__ out)
{
    int w = threadIdx.x >> 6, lane = threadIdx.x & 63;
    int row = blockIdx.x*4 + w;
    int t = targets[row];
    int hidx = t < 2000 ? t : (t < 10000 ? 2000 : 2001);
    int rel0 = min(max(t - 2000, 0), 7999);
    int rel1 = min(max(t - 10000, 0), 40256);

    // head dot, K=1024: 16 bf16 per lane
    float dh = 0.f;
    {
        const uint4* xa = (const uint4*)(Xb  + row*1024  + lane*16);
        const uint4* wb = (const uint4*)(hWb + hidx*1024 + lane*16);
        #pragma unroll
        for (int p = 0; p < 2; ++p){
            uint4 xv = xa[p], wv = wb[p];
            dh += dotu(xv.x, wv.x) + dotu(xv.y, wv.y)
                + dotu(xv.z, wv.z) + dotu(xv.w, wv.w);
        }
    }
    // tail0 dot, K=256: 4 bf16 per lane
    float d0;
    {
        uint2 xv = *(const uint2*)(h0b + row*256  + lane*4);
        uint2 wv = *(const uint2*)(e0b + rel0*256 + lane*4);
        d0 = dotu(xv.x, wv.x) + dotu(xv.y, wv.y);
    }
    // tail1 dot, K=64: 1 bf16 per lane
    float d1 = b2f(h1b[row*64 + lane]) * b2f(e1b[rel1*64 + lane]);

    #pragma unroll
    for (int m = 1; m < 64; m <<= 1){
        dh += __shfl_xor(dh, m, 64);
        d0 += __shfl_xor(d0, m, 64);
        d1 += __shfl_xor(d1, m, 64);
    }
    if (lane == 0){
        float lp = dh - log2f(sH[row]);
        if (t >= 2000 && t < 10000) lp += d0 - log2f(s0[row]);
        if (t >= 10000)             lp += d1 - log2f(s1[row]);
        out[row] = LN2 * lp;
    }
}

__global__ void k_loss(const float* __restrict__ out, float* __restrict__ loss){
    __shared__ float red[1024];
    float s = 0.f;
    for (int i = threadIdx.x; i < 4096; i += 1024) s += out[i];
    red[threadIdx.x] = s;
    __syncthreads();
    for (int ofs = 512; ofs > 0; ofs >>= 1){
        if (threadIdx.x < ofs) red[threadIdx.x] += red[threadIdx.x + ofs];
        __syncthreads();
    }
    if (threadIdx.x == 0) loss[0] = -red[0] / 4096.f;
}

// ---------------- host launch ----------------
extern "C" void kernel_launch(void* const* d_in, const int* in_sizes, int n_in,
                              void* d_out, int out_size, void* d_ws, size_t ws_size,
                              hipStream_t stream) {
    const float* X      = (const float*)d_in[0];   // [4096][1024]
    const int*   tgt    = (const int*)  d_in[1];   // [4096]
    const float* headW  = (const float*)d_in[2];   // [2002][1024]
    const float* emb0   = (const float*)d_in[3];   // [8000][256]
    const float* lin0   = (const float*)d_in[4];   // [1024][256]
    const float* emb1   = (const float*)d_in[5];   // [40257][64]
    const float* lin1   = (const float*)d_in[6];   // [1024][64]
    float* out = (float*)d_out;                    // [4097]

    char* ws = (char*)d_ws;
    unsigned short* Xb  = (unsigned short*)(ws + 0);          // 8,388,608 B
    unsigned short* hWb = (unsigned short*)(ws + 8388608);    // 4,100,096 B
    unsigned short* e0b = (unsigned short*)(ws + 12488704);   // 4,096,000 B
    unsigned short* e1b = (unsigned short*)(ws + 16584704);   // 5,152,896 B
    unsigned short* l0T = (unsigned short*)(ws + 21737600);   //   524,288 B
    unsigned short* l1T = (unsigned short*)(ws + 22261888);   //   131,072 B
    unsigned short* h0b = (unsigned short*)(ws + 22392960);   // 2,097,152 B
    unsigned short* h1b = (unsigned short*)(ws + 24490112);   //   524,288 B
    float* sums         = (float*)(ws + 25014400);            // 3*4096 floats
    float* sH = sums, *s0 = sums + 4096, *s1 = sums + 8192;

    hipMemsetAsync(sums, 0, 3*4096*sizeof(float), stream);

    k_convert_scale<<<512, 256, 0, stream>>>(X,     Xb,  4096*1024/4, 1.0f);
    k_convert_scale<<<512, 256, 0, stream>>>(headW, hWb, 2002*1024/4, LOG2E);
    k_convert_scale<<<512, 256, 0, stream>>>(emb0,  e0b, 8000*256/4,  LOG2E);
    k_convert_scale<<<512, 256, 0, stream>>>(emb1,  e1b, 40257*64/4,  LOG2E);
    k_transpose_convert<<<(256*1024+255)/256, 256, 0, stream>>>(lin0, l0T, 256, 256*1024);
    k_transpose_convert<<<(64*1024+255)/256,  256, 0, stream>>>(lin1, l1T, 64,  64*1024);

    k_gemm_store<<<dim3(64, 4), 256, 0, stream>>>(Xb, l0T, h0b, 256);
    k_gemm_store<<<dim3(64, 1), 256, 0, stream>>>(Xb, l1T, h1b, 64);

    k_gemm_sumexp<1024><<<dim3(64, 4), 256, 0, stream>>>(Xb,  hWb, sH, 2002,  8);
    k_gemm_sumexp<256> <<<dim3(64, 4), 256, 0, stream>>>(h0b, e0b, s0, 8000,  32);
    k_gemm_sumexp<64>  <<<dim3(64, 8), 256, 0, stream>>>(h1b, e1b, s1, 40257, 79);

    k_combine<<<1024, 256, 0, stream>>>(Xb, hWb, h0b, e0b, h1b, e1b,
                                        sH, s0, s1, tgt, out);
    k_loss<<<1, 1024, 0, stream>>>(out, out + 4096);
}

// Round 2
// 290.815 us; speedup vs baseline: 1.6820x; 1.6820x over previous
//
#include <hip/hip_runtime.h>

// AdaptiveSoftmax on MI355X — round 2.
// R1 post-mortem: tail1 sumexp 133us with ALL pipes <5% busy, occupancy 11%
// -> latency-bound serialized chunk loop + 12 serialized dispatches.
// R2: (a) one fused sumexp dispatch (head+tail0+tail1, 1536 blocks),
//     (b) single-barrier reg double-buffer for the LDS GEMM paths,
//     (c) tail1 as barrier-free per-wave streaming (A + sums in regs,
//         B fragments loaded straight from global in MFMA layout),
//     (d) all converts fused into k_prep (also zeroes the sum buffers).

typedef __attribute__((ext_vector_type(8))) short short8;
typedef __attribute__((ext_vector_type(4))) float f32x4;

#define LOG2E 1.4426950408889634f
#define LN2   0.6931471805599453f

__device__ __forceinline__ float b2f(unsigned short u){
    return __uint_as_float(((unsigned int)u) << 16);
}
__device__ __forceinline__ unsigned short f2b(float f){
    unsigned int x = __float_as_uint(f);
    x += 0x7fffu + ((x >> 16) & 1u);
    return (unsigned short)(x >> 16);
}
__device__ __forceinline__ float dotu(unsigned int xu, unsigned int wu){
    float a = __uint_as_float(xu << 16) * __uint_as_float(wu << 16);
    float b = __uint_as_float(xu & 0xffff0000u) * __uint_as_float(wu & 0xffff0000u);
    return a + b;
}

// ---------------- prep: all converts + transposes + zero sums ---------------
__global__ __launch_bounds__(256) void k_prep(
    const float* __restrict__ X, const float* __restrict__ headW,
    const float* __restrict__ emb0, const float* __restrict__ emb1,
    const float* __restrict__ lin0, const float* __restrict__ lin1,
    unsigned short* __restrict__ Xb, unsigned short* __restrict__ hWb,
    unsigned short* __restrict__ e0b, unsigned short* __restrict__ e1b,
    unsigned short* __restrict__ l0T, unsigned short* __restrict__ l1T,
    float* __restrict__ sums)
{
    const int NX = 1048576, NH = 512512, NE0 = 512000, NE1 = 644112; // f4 units
    const int NV = NX + NH + NE0 + NE1;   // 2717200
    const int NT0 = 262144, NT1 = 65536;  // transpose elements
    const int NS  = 12288;
    const int total = NV + NT0 + NT1 + NS;
    int stride = gridDim.x * blockDim.x;
    for (int i = blockIdx.x*blockDim.x + threadIdx.x; i < total; i += stride){
        if (i < NV){
            const float* src; unsigned short* dst; int off; float sc;
            if (i < NX)            { src = X;     dst = Xb;  off = i;            sc = 1.0f;  }
            else if (i < NX+NH)    { src = headW; dst = hWb; off = i-NX;         sc = LOG2E; }
            else if (i < NX+NH+NE0){ src = emb0;  dst = e0b; off = i-NX-NH;      sc = LOG2E; }
            else                   { src = emb1;  dst = e1b; off = i-NX-NH-NE0;  sc = LOG2E; }
            float4 v = ((const float4*)src)[off];
            ushort4 o;
            o.x = f2b(v.x*sc); o.y = f2b(v.y*sc);
            o.z = f2b(v.z*sc); o.w = f2b(v.w*sc);
            ((ushort4*)dst)[off] = o;
        } else if (i < NV + NT0){
            int idx = i - NV;                 // c*1024 + d
            int c = idx >> 10, d = idx & 1023;
            l0T[idx] = f2b(lin0[d*256 + c]);
        } else if (i < NV + NT0 + NT1){
            int idx = i - NV - NT0;
            int c = idx >> 10, d = idx & 1023;
            l1T[idx] = f2b(lin1[d*64 + c]);
        } else {
            sums[i - NV - NT0 - NT1] = 0.f;
        }
    }
}

// ---------------- h-GEMMs (K=1024, store bf16): h0 and h1 fused -------------
__global__ __launch_bounds__(256) void k_hgemm(
    const unsigned short* __restrict__ A,    // Xb [4096][1024]
    const unsigned short* __restrict__ B0, unsigned short* __restrict__ C0,
    const unsigned short* __restrict__ B1, unsigned short* __restrict__ C1)
{
    constexpr int K = 1024;
    __shared__ __align__(16) unsigned short As[64*64];
    __shared__ __align__(16) unsigned short Bs[64*64];

    const int yy = blockIdx.y;
    const unsigned short* B = (yy < 4) ? B0 : B1;
    unsigned short* C = (yy < 4) ? C0 : C1;
    const int M  = (yy < 4) ? 256 : 64;
    const int cb = (yy < 4) ? yy : 0;

    const int tid  = threadIdx.x;
    const int lane = tid & 63;
    const int w    = tid >> 6;
    const int waveR = w >> 1, waveC = w & 1;
    const int quad  = lane >> 4, l16 = lane & 15;
    const int row0  = blockIdx.x * 64;

    f32x4 acc[2][2];
    #pragma unroll
    for (int i = 0; i < 2; ++i)
    #pragma unroll
    for (int j = 0; j < 2; ++j)
        acc[i][j] = (f32x4){0.f, 0.f, 0.f, 0.f};

    for (int kc = 0; kc < K/64; ++kc){
        __syncthreads();
        #pragma unroll
        for (int it = 0; it < 2; ++it){
            int idx = tid + it*256;
            int r = idx >> 3, g = idx & 7;
            *((uint4*)&As[r*64 + ((g ^ (r & 7)) << 3)]) =
                *(const uint4*)(A + (row0 + r)*K + kc*64 + g*8);
            *((uint4*)&Bs[r*64 + ((g ^ (r & 7)) << 3)]) =
                *(const uint4*)(B + (cb*64 + r)*K + kc*64 + g*8);
        }
        __syncthreads();
        #pragma unroll
        for (int ks = 0; ks < 2; ++ks){
            short8 a[2], b[2];
            #pragma unroll
            for (int i = 0; i < 2; ++i){
                int r = waveR*32 + i*16 + l16;
                int g = ks*4 + quad;
                a[i] = *(const short8*)&As[r*64 + ((g ^ (r & 7)) << 3)];
            }
            #pragma unroll
            for (int j = 0; j < 2; ++j){
                int r = waveC*32 + j*16 + l16;
                int g = ks*4 + quad;
                b[j] = *(const short8*)&Bs[r*64 + ((g ^ (r & 7)) << 3)];
            }
            #pragma unroll
            for (int i = 0; i < 2; ++i)
            #pragma unroll
            for (int j = 0; j < 2; ++j)
                acc[i][j] = __builtin_amdgcn_mfma_f32_16x16x32_bf16(
                    a[i], b[j], acc[i][j], 0, 0, 0);
        }
    }
    #pragma unroll
    for (int i = 0; i < 2; ++i)
    #pragma unroll
    for (int j = 0; j < 2; ++j)
    #pragma unroll
    for (int r = 0; r < 4; ++r){
        int row = row0 + waveR*32 + i*16 + quad*4 + r;
        int col = cb*64 + waveC*32 + j*16 + l16;
        C[row*M + col] = f2b(acc[i][j][r]);
    }
}

// ------------- LDS GEMM+sumexp path, single-barrier reg double-buffer -------
template<int K>
__device__ __forceinline__ void sumexp_lds(
    const unsigned short* __restrict__ A,   // [4096][K]
    const unsigned short* __restrict__ B,   // [M][K] (pre-scaled by log2e)
    float* __restrict__ s_out, int M,
    int rowb, int cb0, int cb1,
    unsigned short* __restrict__ As,        // [2][64*64]
    unsigned short* __restrict__ Bs)
{
    constexpr int KCH = K / 64;
    constexpr int LK  = (KCH == 16) ? 4 : 2;   // log2(KCH): K=1024 -> 4, K=256 -> 2
    const int tid  = threadIdx.x;
    const int lane = tid & 63, w = tid >> 6;
    const int waveR = w >> 1, waveC = w & 1;
    const int quad  = lane >> 4, l16 = lane & 15;
    const int row0  = rowb * 64;
    const int nit   = (cb1 - cb0) << LK;

    float s_loc[8];
    #pragma unroll
    for (int i = 0; i < 8; ++i) s_loc[i] = 0.f;
    f32x4 acc[2][2];
    #pragma unroll
    for (int i = 0; i < 2; ++i)
    #pragma unroll
    for (int j = 0; j < 2; ++j) acc[i][j] = (f32x4){0.f,0.f,0.f,0.f};

    // staging geometry: 256 threads cover rows 0..31 (half 0) and 32..63
    const int srow = tid >> 3;
    const int sg   = tid & 7;
    const int so0 = srow*64 + ((sg ^ (srow & 7)) << 3);
    const int so1 = (srow+32)*64 + ((sg ^ ((srow+32) & 7)) << 3);

    // fragment LDS read offsets (fixed per thread)
    int aoff[2][2], boff[2][2];
    #pragma unroll
    for (int x = 0; x < 2; ++x)
    #pragma unroll
    for (int ks = 0; ks < 2; ++ks){
        int ra = waveR*32 + x*16 + l16;
        int rb = waveC*32 + x*16 + l16;
        int g  = ks*4 + quad;
        aoff[x][ks] = ra*64 + ((g ^ (ra & 7)) << 3);
        boff[x][ks] = rb*64 + ((g ^ (rb & 7)) << 3);
    }

    uint4 rA0, rA1, rB0, rB1;
    auto loadAB = [&](int it){
        int cb = cb0 + (it >> LK);
        int kc = it & (KCH - 1);
        const unsigned short* ap = A + (row0 + srow)*K + kc*64 + sg*8;
        rA0 = *(const uint4*)ap;
        rA1 = *(const uint4*)(ap + 32*K);
        int br = cb*64 + srow;
        const unsigned short* bp = B + br*K + kc*64 + sg*8;
        rB0 = (br      < M) ? *(const uint4*)bp           : (uint4){0,0,0,0};
        rB1 = (br + 32 < M) ? *(const uint4*)(bp + 32*K)  : (uint4){0,0,0,0};
    };
    auto writeAB = [&](int it){
        unsigned short* Ad = As + (it & 1)*4096;
        unsigned short* Bd = Bs + (it & 1)*4096;
        *(uint4*)(Ad + so0) = rA0;
        *(uint4*)(Ad + so1) = rA1;
        *(uint4*)(Bd + so0) = rB0;
        *(uint4*)(Bd + so1) = rB1;
    };

    loadAB(0);
    writeAB(0);
    if (nit > 1) loadAB(1);
    __syncthreads();

    for (int it = 0; it < nit; ++it){
        if (it + 1 < nit) writeAB(it + 1);   // other buffer — safe pre-barrier
        if (it + 2 < nit) loadAB(it + 2);
        const unsigned short* Ac = As + (it & 1)*4096;
        const unsigned short* Bc = Bs + (it & 1)*4096;
        #pragma unroll
        for (int ks = 0; ks < 2; ++ks){
            short8 a0 = *(const short8*)(Ac + aoff[0][ks]);
            short8 a1 = *(const short8*)(Ac + aoff[1][ks]);
            short8 b0 = *(const short8*)(Bc + boff[0][ks]);
            short8 b1 = *(const short8*)(Bc + boff[1][ks]);
            acc[0][0] = __builtin_amdgcn_mfma_f32_16x16x32_bf16(a0, b0, acc[0][0], 0,0,0);
            acc[0][1] = __builtin_amdgcn_mfma_f32_16x16x32_bf16(a0, b1, acc[0][1], 0,0,0);
            acc[1][0] = __builtin_amdgcn_mfma_f32_16x16x32_bf16(a1, b0, acc[1][0], 0,0,0);
            acc[1][1] = __builtin_amdgcn_mfma_f32_16x16x32_bf16(a1, b1, acc[1][1], 0,0,0);
        }
        if ((it & (KCH - 1)) == (KCH - 1)){
            int cb = cb0 + (it >> LK);
            if ((cb + 1)*64 <= M){
                #pragma unroll
                for (int i = 0; i < 2; ++i)
                #pragma unroll
                for (int j = 0; j < 2; ++j)
                #pragma unroll
                for (int r = 0; r < 4; ++r)
                    s_loc[i*4 + r] += exp2f(acc[i][j][r]);
            } else {
                #pragma unroll
                for (int j = 0; j < 2; ++j){
                    int col = cb*64 + waveC*32 + j*16 + l16;
                    if (col < M){
                        #pragma unroll
                        for (int i = 0; i < 2; ++i)
                        #pragma unroll
                        for (int r = 0; r < 4; ++r)
                            s_loc[i*4 + r] += exp2f(acc[i][j][r]);
                    }
                }
            }
            #pragma unroll
            for (int i = 0; i < 2; ++i)
            #pragma unroll
            for (int j = 0; j < 2; ++j) acc[i][j] = (f32x4){0.f,0.f,0.f,0.f};
        }
        __syncthreads();
    }

    #pragma unroll
    for (int k = 0; k < 8; ++k){
        #pragma unroll
        for (int m = 1; m < 16; m <<= 1)
            s_loc[k] += __shfl_xor(s_loc[k], m, 64);
    }
    if (l16 < 8){
        int i = l16 >> 2, r = l16 & 3;
        int row = row0 + waveR*32 + i*16 + quad*4 + r;
        atomicAdd(&s_out[row], s_loc[l16]);
    }
}

// ------------- tail1 (K=64): barrier-free per-wave streaming ----------------
__device__ __forceinline__ void sumexp_stream64(
    const unsigned short* __restrict__ A,   // h1b [4096][64]
    const unsigned short* __restrict__ B,   // e1b [40257][64] (scaled)
    float* __restrict__ s_out, int wid)     // wid in [0, 2048)
{
    const int M = 40257;
    const int lane = threadIdx.x & 63;
    const int quad = lane >> 4, l16 = lane & 15;
    const int rowg  = wid >> 6;             // 0..31, 128 rows each
    const int split = wid & 63;             // 0..63
    // 2517 groups of 16 cols; splits 0..20 take 40 groups, rest take 39
    const int g0 = split*39 + min(split, 21);
    const int g1 = g0 + 39 + (split < 21 ? 1 : 0);
    const int row0 = rowg * 128;

    short8 a[8][2];
    #pragma unroll
    for (int i = 0; i < 8; ++i)
    #pragma unroll
    for (int ks = 0; ks < 2; ++ks)
        a[i][ks] = *(const short8*)(A + (row0 + i*16 + l16)*64 + ks*32 + quad*8);

    f32x4 sums[8];
    #pragma unroll
    for (int i = 0; i < 8; ++i) sums[i] = (f32x4){0.f,0.f,0.f,0.f};

    short8 bcur0, bcur1, bnxt0, bnxt1;
    auto loadB = [&](int g, short8& d0, short8& d1){
        int n = g*16 + l16; if (n > M-1) n = M-1;
        const unsigned short* p = B + n*64 + quad*8;
        d0 = *(const short8*)p;
        d1 = *(const short8*)(p + 32);
    };
    loadB(g0, bcur0, bcur1);
    for (int g = g0; g < g1; ++g){
        if (g + 1 < g1) loadB(g + 1, bnxt0, bnxt1);
        f32x4 acc[8];
        #pragma unroll
        for (int i = 0; i < 8; ++i) acc[i] = (f32x4){0.f,0.f,0.f,0.f};
        #pragma unroll
        for (int i = 0; i < 8; ++i)
            acc[i] = __builtin_amdgcn_mfma_f32_16x16x32_bf16(a[i][0], bcur0, acc[i], 0,0,0);
        #pragma unroll
        for (int i = 0; i < 8; ++i)
            acc[i] = __builtin_amdgcn_mfma_f32_16x16x32_bf16(a[i][1], bcur1, acc[i], 0,0,0);
        if (g*16 + l16 < M){
            #pragma unroll
            for (int i = 0; i < 8; ++i){
                sums[i][0] += exp2f(acc[i][0]);
                sums[i][1] += exp2f(acc[i][1]);
                sums[i][2] += exp2f(acc[i][2]);
                sums[i][3] += exp2f(acc[i][3]);
            }
        }
        bcur0 = bnxt0; bcur1 = bnxt1;
    }

    #pragma unroll
    for (int i = 0; i < 8; ++i){
        #pragma unroll
        for (int r = 0; r < 4; ++r){
            float v = sums[i][r];
            v += __shfl_xor(v, 1, 64);
            v += __shfl_xor(v, 2, 64);
            v += __shfl_xor(v, 4, 64);
            v += __shfl_xor(v, 8, 64);
            if (l16 == 0)
                atomicAdd(&s_out[row0 + i*16 + quad*4 + r], v);
        }
    }
}

// ------------- fused sumexp dispatch ----------------------------------------
__global__ __launch_bounds__(256) void k_sumexp(
    const unsigned short* __restrict__ Xb,  const unsigned short* __restrict__ hWb,
    const unsigned short* __restrict__ h0b, const unsigned short* __restrict__ e0b,
    const unsigned short* __restrict__ h1b, const unsigned short* __restrict__ e1b,
    float* __restrict__ sH, float* __restrict__ s0, float* __restrict__ s1)
{
    __shared__ __align__(16) unsigned short As[2*4096];
    __shared__ __align__(16) unsigned short Bs[2*4096];
    const int b = blockIdx.x;
    if (b < 512){
        // head: K=1024, M=2002 (32 chunks), 8 col-splits x 4 chunks
        int rowb = b >> 3, split = b & 7;
        sumexp_lds<1024>(Xb, hWb, sH, 2002, rowb, split*4, split*4 + 4, As, Bs);
    } else if (b < 1024){
        // tail0: K=256, M=8000 (125 chunks), 8 col-splits x <=16 chunks
        int bb = b - 512;
        int rowb = bb >> 3, split = bb & 7;
        int cb0 = split*16, cb1 = min(125, cb0 + 16);
        sumexp_lds<256>(h0b, e0b, s0, 8000, rowb, cb0, cb1, As, Bs);
    } else {
        int wid = (b - 1024)*4 + (threadIdx.x >> 6);
        sumexp_stream64(h1b, e1b, s1, wid);
    }
}

// ---------------- combine: target logits + assemble log-probs ---------------
__global__ __launch_bounds__(256) void k_combine(
    const unsigned short* __restrict__ Xb,   // [4096][1024]
    const unsigned short* __restrict__ hWb,  // [2002][1024] (scaled)
    const unsigned short* __restrict__ h0b,  // [4096][256]
    const unsigned short* __restrict__ e0b,  // [8000][256] (scaled)
    const unsigned short* __restrict__ h1b,  // [4096][64]
    const unsigned short* __restrict__ e1b,  // [40257][64] (scaled)
    const float* __restrict__ sH, const float* __restrict__ s0,
    const float* __restrict__ s1,
    const int* __restrict__ targets, float* __restrict__ out)
{
    int w = threadIdx.x >> 6, lane = threadIdx.x & 63;
    int row = blockIdx.x*4 + w;
    int t = targets[row];
    int hidx = t < 2000 ? t : (t < 10000 ? 2000 : 2001);
    int rel0 = min(max(t - 2000, 0), 7999);
    int rel1 = min(max(t - 10000, 0), 40256);

    float dh = 0.f;
    {
        const uint4* xa = (const uint4*)(Xb  + row*1024  + lane*16);
        const uint4* wb = (const uint4*)(hWb + hidx*1024 + lane*16);
        #pragma unroll
        for (int p = 0; p < 2; ++p){
            uint4 xv = xa[p], wv = wb[p];
            dh += dotu(xv.x, wv.x) + dotu(xv.y, wv.y)
                + dotu(xv.z, wv.z) + dotu(xv.w, wv.w);
        }
    }
    float d0;
    {
        uint2 xv = *(const uint2*)(h0b + row*256  + lane*4);
        uint2 wv = *(const uint2*)(e0b + rel0*256 + lane*4);
        d0 = dotu(xv.x, wv.x) + dotu(xv.y, wv.y);
    }
    float d1 = b2f(h1b[row*64 + lane]) * b2f(e1b[rel1*64 + lane]);

    #pragma unroll
    for (int m = 1; m < 64; m <<= 1){
        dh += __shfl_xor(dh, m, 64);
        d0 += __shfl_xor(d0, m, 64);
        d1 += __shfl_xor(d1, m, 64);
    }
    if (lane == 0){
        float lp = dh - log2f(sH[row]);
        if (t >= 2000 && t < 10000) lp += d0 - log2f(s0[row]);
        if (t >= 10000)             lp += d1 - log2f(s1[row]);
        out[row] = LN2 * lp;
    }
}

__global__ void k_loss(const float* __restrict__ out, float* __restrict__ loss){
    __shared__ float red[1024];
    float s = 0.f;
    for (int i = threadIdx.x; i < 4096; i += 1024) s += out[i];
    red[threadIdx.x] = s;
    __syncthreads();
    for (int ofs = 512; ofs > 0; ofs >>= 1){
        if (threadIdx.x < ofs) red[threadIdx.x] += red[threadIdx.x + ofs];
        __syncthreads();
    }
    if (threadIdx.x == 0) loss[0] = -red[0] / 4096.f;
}

// ---------------- host launch ----------------
extern "C" void kernel_launch(void* const* d_in, const int* in_sizes, int n_in,
                              void* d_out, int out_size, void* d_ws, size_t ws_size,
                              hipStream_t stream) {
    const float* X      = (const float*)d_in[0];   // [4096][1024]
    const int*   tgt    = (const int*)  d_in[1];   // [4096]
    const float* headW  = (const float*)d_in[2];   // [2002][1024]
    const float* emb0   = (const float*)d_in[3];   // [8000][256]
    const float* lin0   = (const float*)d_in[4];   // [1024][256]
    const float* emb1   = (const float*)d_in[5];   // [40257][64]
    const float* lin1   = (const float*)d_in[6];   // [1024][64]
    float* out = (float*)d_out;                    // [4097]

    char* ws = (char*)d_ws;
    unsigned short* Xb  = (unsigned short*)(ws + 0);          // 8,388,608 B
    unsigned short* hWb = (unsigned short*)(ws + 8388608);    // 4,100,096 B
    unsigned short* e0b = (unsigned short*)(ws + 12488704);   // 4,096,000 B
    unsigned short* e1b = (unsigned short*)(ws + 16584704);   // 5,152,896 B
    unsigned short* l0T = (unsigned short*)(ws + 21737600);   //   524,288 B
    unsigned short* l1T = (unsigned short*)(ws + 22261888);   //   131,072 B
    unsigned short* h0b = (unsigned short*)(ws + 22392960);   // 2,097,152 B
    unsigned short* h1b = (unsigned short*)(ws + 24490112);   //   524,288 B
    float* sums         = (float*)(ws + 25014400);            // 3*4096 floats
    float* sH = sums, *s0 = sums + 4096, *s1 = sums + 8192;

    k_prep<<<2048, 256, 0, stream>>>(X, headW, emb0, emb1, lin0, lin1,
                                     Xb, hWb, e0b, e1b, l0T, l1T, sums);
    k_hgemm<<<dim3(64, 5), 256, 0, stream>>>(Xb, l0T, h0b, l1T, h1b);
    k_sumexp<<<1536, 256, 0, stream>>>(Xb, hWb, h0b, e0b, h1b, e1b, sH, s0, s1);
    k_combine<<<1024, 256, 0, stream>>>(Xb, hWb, h0b, e0b, h1b, e1b,
                                        sH, s0, s1, tgt, out);
    k_loss<<<1, 1024, 0, stream>>>(out, out + 4096);
}

// Round 3
// 234.230 us; speedup vs baseline: 2.0884x; 1.2416x over previous
//
#include <hip/hip_runtime.h>

// AdaptiveSoftmax on MI355X — round 3.
// R2 post-mortem: k_sumexp 182us, MfmaUtil 12.8% (=23us MFMA, the ideal work),
// VALUBusy 48% (=87us!). exp2f lowers to OCML (~10 VALU ops) -> VALU-pacing.
// R3: raw v_exp_f32, distance-2 prefetch in LDS GEMM, depth-2 B prefetch in
// tail1 stream, interleaved phase->block mapping, LDS-tiled lin transpose.

typedef __attribute__((ext_vector_type(8))) short short8;
typedef __attribute__((ext_vector_type(4))) float f32x4;

#define LOG2E 1.4426950408889634f
#define LN2   0.6931471805599453f

__device__ __forceinline__ float b2f(unsigned short u){
    return __uint_as_float(((unsigned int)u) << 16);
}
__device__ __forceinline__ unsigned short f2b(float f){
    unsigned int x = __float_as_uint(f);
    x += 0x7fffu + ((x >> 16) & 1u);
    return (unsigned short)(x >> 16);
}
__device__ __forceinline__ float dotu(unsigned int xu, unsigned int wu){
    float a = __uint_as_float(xu << 16) * __uint_as_float(wu << 16);
    float b = __uint_as_float(xu & 0xffff0000u) * __uint_as_float(wu & 0xffff0000u);
    return a + b;
}
// single v_exp_f32 — inputs are bounded logits, no OCML range fixup needed
__device__ __forceinline__ float fexp2(float x){
#if __has_builtin(__builtin_amdgcn_exp2f)
    return __builtin_amdgcn_exp2f(x);
#else
    float r; asm("v_exp_f32 %0, %1" : "=v"(r) : "v"(x)); return r;
#endif
}

// ---------------- prep: converts + LDS-tiled transposes + zero sums ---------
__global__ __launch_bounds__(256) void k_prep(
    const float* __restrict__ X, const float* __restrict__ headW,
    const float* __restrict__ emb0, const float* __restrict__ emb1,
    const float* __restrict__ lin0, const float* __restrict__ lin1,
    unsigned short* __restrict__ Xb, unsigned short* __restrict__ hWb,
    unsigned short* __restrict__ e0b, unsigned short* __restrict__ e1b,
    unsigned short* __restrict__ l0T, unsigned short* __restrict__ l1T,
    float* __restrict__ sums)
{
    __shared__ unsigned short tileT[64][65];   // +1 pad: 2-way max on writes
    const int b = blockIdx.x, t = threadIdx.x;
    if (b < 80){
        // transpose lin0 [1024][256] -> l0T [256][1024], lin1 -> l1T [64][1024]
        const float* src; unsigned short* dst; int C, tx, ty;
        if (b < 64){ src = lin0; dst = l0T; C = 256; tx = b & 3; ty = b >> 2; }
        else       { src = lin1; dst = l1T; C = 64;  tx = 0;     ty = b - 64; }
        #pragma unroll
        for (int e = 0; e < 16; ++e){
            int idx = t + e*256, r = idx >> 6, c = idx & 63;
            tileT[c][r] = f2b(src[(ty*64 + r)*C + tx*64 + c]);   // coalesced read
        }
        __syncthreads();
        #pragma unroll
        for (int e = 0; e < 16; ++e){
            int idx = t + e*256, cc = idx >> 6, rr = idx & 63;
            dst[(tx*64 + cc)*1024 + ty*64 + rr] = tileT[cc][rr]; // coalesced write
        }
        return;
    }
    const int NX = 1048576, NH = 512512, NE0 = 512000, NE1 = 644112; // float4 units
    const int NV = NX + NH + NE0 + NE1;
    const int NS = 12288;
    const int total = NV + NS;
    int stride = (gridDim.x - 80) * blockDim.x;
    for (int i = (b - 80)*blockDim.x + t; i < total; i += stride){
        if (i < NV){
            const float* src; unsigned short* dst; int off; float sc;
            if (i < NX)            { src = X;     dst = Xb;  off = i;           sc = 1.0f;  }
            else if (i < NX+NH)    { src = headW; dst = hWb; off = i-NX;        sc = LOG2E; }
            else if (i < NX+NH+NE0){ src = emb0;  dst = e0b; off = i-NX-NH;     sc = LOG2E; }
            else                   { src = emb1;  dst = e1b; off = i-NX-NH-NE0; sc = LOG2E; }
            float4 v = ((const float4*)src)[off];
            ushort4 o;
            o.x = f2b(v.x*sc); o.y = f2b(v.y*sc);
            o.z = f2b(v.z*sc); o.w = f2b(v.w*sc);
            ((ushort4*)dst)[off] = o;
        } else {
            sums[i - NV] = 0.f;
        }
    }
}

// ---------------- h-GEMMs (K=1024, store bf16): h0 and h1 fused -------------
__global__ __launch_bounds__(256) void k_hgemm(
    const unsigned short* __restrict__ A,    // Xb [4096][1024]
    const unsigned short* __restrict__ B0, unsigned short* __restrict__ C0,
    const unsigned short* __restrict__ B1, unsigned short* __restrict__ C1)
{
    constexpr int K = 1024;
    __shared__ __align__(16) unsigned short As[64*64];
    __shared__ __align__(16) unsigned short Bs[64*64];

    const int yy = blockIdx.y;
    const unsigned short* B = (yy < 4) ? B0 : B1;
    unsigned short* C = (yy < 4) ? C0 : C1;
    const int M  = (yy < 4) ? 256 : 64;
    const int cb = (yy < 4) ? yy : 0;

    const int tid  = threadIdx.x;
    const int lane = tid & 63;
    const int w    = tid >> 6;
    const int waveR = w >> 1, waveC = w & 1;
    const int quad  = lane >> 4, l16 = lane & 15;
    const int row0  = blockIdx.x * 64;

    f32x4 acc[2][2];
    #pragma unroll
    for (int i = 0; i < 2; ++i)
    #pragma unroll
    for (int j = 0; j < 2; ++j)
        acc[i][j] = (f32x4){0.f, 0.f, 0.f, 0.f};

    for (int kc = 0; kc < K/64; ++kc){
        __syncthreads();
        #pragma unroll
        for (int it = 0; it < 2; ++it){
            int idx = tid + it*256;
            int r = idx >> 3, g = idx & 7;
            *((uint4*)&As[r*64 + ((g ^ (r & 7)) << 3)]) =
                *(const uint4*)(A + (row0 + r)*K + kc*64 + g*8);
            *((uint4*)&Bs[r*64 + ((g ^ (r & 7)) << 3)]) =
                *(const uint4*)(B + (cb*64 + r)*K + kc*64 + g*8);
        }
        __syncthreads();
        #pragma unroll
        for (int ks = 0; ks < 2; ++ks){
            short8 a[2], b[2];
            #pragma unroll
            for (int i = 0; i < 2; ++i){
                int r = waveR*32 + i*16 + l16;
                int g = ks*4 + quad;
                a[i] = *(const short8*)&As[r*64 + ((g ^ (r & 7)) << 3)];
            }
            #pragma unroll
            for (int j = 0; j < 2; ++j){
                int r = waveC*32 + j*16 + l16;
                int g = ks*4 + quad;
                b[j] = *(const short8*)&Bs[r*64 + ((g ^ (r & 7)) << 3)];
            }
            #pragma unroll
            for (int i = 0; i < 2; ++i)
            #pragma unroll
            for (int j = 0; j < 2; ++j)
                acc[i][j] = __builtin_amdgcn_mfma_f32_16x16x32_bf16(
                    a[i], b[j], acc[i][j], 0, 0, 0);
        }
    }
    #pragma unroll
    for (int i = 0; i < 2; ++i)
    #pragma unroll
    for (int j = 0; j < 2; ++j)
    #pragma unroll
    for (int r = 0; r < 4; ++r){
        int row = row0 + waveR*32 + i*16 + quad*4 + r;
        int col = cb*64 + waveC*32 + j*16 + l16;
        C[row*M + col] = f2b(acc[i][j][r]);
    }
}

// ------------- LDS GEMM+sumexp, distance-2 prefetch, 1 barrier/k-step -------
template<int K>
__device__ __forceinline__ void sumexp_lds(
    const unsigned short* __restrict__ A,   // [4096][K]
    const unsigned short* __restrict__ B,   // [M][K] (pre-scaled by log2e)
    float* __restrict__ s_out, int M,
    int rowb, int cb0, int cb1,
    unsigned short* __restrict__ As,        // [2][64*64]
    unsigned short* __restrict__ Bs)
{
    constexpr int KCH = K / 64;
    constexpr int LK  = (KCH == 16) ? 4 : 2;
    static_assert(KCH == 16 || KCH == 4, "");
    const int tid  = threadIdx.x;
    const int lane = tid & 63, w = tid >> 6;
    const int waveR = w >> 1, waveC = w & 1;
    const int quad  = lane >> 4, l16 = lane & 15;
    const int row0  = rowb * 64;
    const int nit   = (cb1 - cb0) << LK;    // even, >= 52 in all uses

    float s_loc[8];
    #pragma unroll
    for (int i = 0; i < 8; ++i) s_loc[i] = 0.f;
    f32x4 acc[2][2];
    #pragma unroll
    for (int i = 0; i < 2; ++i)
    #pragma unroll
    for (int j = 0; j < 2; ++j) acc[i][j] = (f32x4){0.f,0.f,0.f,0.f};

    const int srow = tid >> 3;
    const int sg   = tid & 7;
    const int so0 = srow*64 + ((sg ^ (srow & 7)) << 3);
    const int so1 = (srow+32)*64 + ((sg ^ ((srow+32) & 7)) << 3);

    int aoff[2][2], boff[2][2];
    #pragma unroll
    for (int x = 0; x < 2; ++x)
    #pragma unroll
    for (int ks = 0; ks < 2; ++ks){
        int ra = waveR*32 + x*16 + l16;
        int rb = waveC*32 + x*16 + l16;
        int g  = ks*4 + quad;
        aoff[x][ks] = ra*64 + ((g ^ (ra & 7)) << 3);
        boff[x][ks] = rb*64 + ((g ^ (rb & 7)) << 3);
    }

    // two staging register sets -> vmcnt wait lands 2 compute bodies after issue
    uint4 A0a, A1a, B0a, B1a, A0b, A1b, B0b, B1b;
    auto loadAB = [&](int it, uint4& A0, uint4& A1, uint4& B0, uint4& B1){
        int cb = cb0 + (it >> LK);
        int kc = it & (KCH - 1);
        const unsigned short* ap = A + (row0 + srow)*K + kc*64 + sg*8;
        A0 = *(const uint4*)ap;
        A1 = *(const uint4*)(ap + 32*K);
        int br = cb*64 + srow;
        const unsigned short* bp = B + br*K + kc*64 + sg*8;
        B0 = (br      < M) ? *(const uint4*)bp          : (uint4){0,0,0,0};
        B1 = (br + 32 < M) ? *(const uint4*)(bp + 32*K) : (uint4){0,0,0,0};
    };
    auto writeAB = [&](int it, uint4 A0, uint4 A1, uint4 B0, uint4 B1){
        unsigned short* Ad = As + (it & 1)*4096;
        unsigned short* Bd = Bs + (it & 1)*4096;
        *(uint4*)(Ad + so0) = A0; *(uint4*)(Ad + so1) = A1;
        *(uint4*)(Bd + so0) = B0; *(uint4*)(Bd + so1) = B1;
    };
    auto compute = [&](int buf){
        const unsigned short* Ac = As + buf*4096;
        const unsigned short* Bc = Bs + buf*4096;
        #pragma unroll
        for (int ks = 0; ks < 2; ++ks){
            short8 a0 = *(const short8*)(Ac + aoff[0][ks]);
            short8 a1 = *(const short8*)(Ac + aoff[1][ks]);
            short8 b0 = *(const short8*)(Bc + boff[0][ks]);
            short8 b1 = *(const short8*)(Bc + boff[1][ks]);
            acc[0][0] = __builtin_amdgcn_mfma_f32_16x16x32_bf16(a0, b0, acc[0][0], 0,0,0);
            acc[0][1] = __builtin_amdgcn_mfma_f32_16x16x32_bf16(a0, b1, acc[0][1], 0,0,0);
            acc[1][0] = __builtin_amdgcn_mfma_f32_16x16x32_bf16(a1, b0, acc[1][0], 0,0,0);
            acc[1][1] = __builtin_amdgcn_mfma_f32_16x16x32_bf16(a1, b1, acc[1][1], 0,0,0);
        }
    };
    auto epilogue = [&](int it){   // only called when (it & (KCH-1)) == KCH-1
        int cb = cb0 + (it >> LK);
        if ((cb + 1)*64 <= M){
            #pragma unroll
            for (int i = 0; i < 2; ++i)
            #pragma unroll
            for (int j = 0; j < 2; ++j)
            #pragma unroll
            for (int r = 0; r < 4; ++r)
                s_loc[i*4 + r] += fexp2(acc[i][j][r]);
        } else {
            #pragma unroll
            for (int j = 0; j < 2; ++j){
                int col = cb*64 + waveC*32 + j*16 + l16;
                if (col < M){
                    #pragma unroll
                    for (int i = 0; i < 2; ++i)
                    #pragma unroll
                    for (int r = 0; r < 4; ++r)
                        s_loc[i*4 + r] += fexp2(acc[i][j][r]);
                }
            }
        }
        #pragma unroll
        for (int i = 0; i < 2; ++i)
        #pragma unroll
        for (int j = 0; j < 2; ++j) acc[i][j] = (f32x4){0.f,0.f,0.f,0.f};
    };

    loadAB(0, A0a, A1a, B0a, B1a);
    writeAB(0, A0a, A1a, B0a, B1a);
    loadAB(1, A0b, A1b, B0b, B1b);
    loadAB(2, A0a, A1a, B0a, B1a);
    __syncthreads();

    for (int it = 0; it < nit; it += 2){
        // half 1: compute buf0; stage buf1 from set b; refill set b (it+3)
        writeAB(it + 1, A0b, A1b, B0b, B1b);
        if (it + 3 < nit) loadAB(it + 3, A0b, A1b, B0b, B1b);
        compute(0);
        __syncthreads();
        // half 2: compute buf1; stage buf0 from set a; refill set a (it+4)
        if (it + 2 < nit) writeAB(it + 2, A0a, A1a, B0a, B1a);
        if (it + 4 < nit) loadAB(it + 4, A0a, A1a, B0a, B1a);
        compute(1);
        if (((it + 1) & (KCH - 1)) == (KCH - 1)) epilogue(it + 1); // chunk ends on odd it
        __syncthreads();
    }

    #pragma unroll
    for (int k = 0; k < 8; ++k){
        #pragma unroll
        for (int m = 1; m < 16; m <<= 1)
            s_loc[k] += __shfl_xor(s_loc[k], m, 64);
    }
    if (l16 < 8){
        int i = l16 >> 2, r = l16 & 3;
        int row = row0 + waveR*32 + i*16 + quad*4 + r;
        atomicAdd(&s_out[row], s_loc[l16]);
    }
}

// ------------- tail1 (K=64): barrier-free streaming, 64 rows/wave -----------
__device__ __forceinline__ void sumexp_stream64(
    const unsigned short* __restrict__ A,   // h1b [4096][64]
    const unsigned short* __restrict__ B,   // e1b [40257][64] (scaled)
    float* __restrict__ s_out, int wid)     // wid in [0, 4096)
{
    const int M = 40257;
    const int lane = threadIdx.x & 63;
    const int quad = lane >> 4, l16 = lane & 15;
    const int rowg  = wid >> 6;             // 0..63, 64 rows each
    const int split = wid & 63;             // 0..63
    // 2517 col-groups of 16: splits 0..20 take 40, rest take 39
    const int g0 = split*39 + min(split, 21);
    const int g1 = g0 + 39 + (split < 21 ? 1 : 0);
    const int row0 = rowg * 64;

    short8 a[4][2];
    #pragma unroll
    for (int i = 0; i < 4; ++i)
    #pragma unroll
    for (int ks = 0; ks < 2; ++ks)
        a[i][ks] = *(const short8*)(A + (row0 + i*16 + l16)*64 + ks*32 + quad*8);

    f32x4 sums[4];
    #pragma unroll
    for (int i = 0; i < 4; ++i) sums[i] = (f32x4){0.f,0.f,0.f,0.f};

    short8 p0a, p1a, p0b, p1b;   // depth-2 B prefetch ring
    auto loadB = [&](int g, short8& d0, short8& d1){
        int n = g*16 + l16; if (n > M-1) n = M-1;
        const unsigned short* p = B + n*64 + quad*8;
        d0 = *(const short8*)p;
        d1 = *(const short8*)(p + 32);
    };
    auto body = [&](int g, short8 b0, short8 b1){
        f32x4 acc[4];
        #pragma unroll
        for (int i = 0; i < 4; ++i) acc[i] = (f32x4){0.f,0.f,0.f,0.f};
        #pragma unroll
        for (int i = 0; i < 4; ++i)
            acc[i] = __builtin_amdgcn_mfma_f32_16x16x32_bf16(a[i][0], b0, acc[i], 0,0,0);
        #pragma unroll
        for (int i = 0; i < 4; ++i)
            acc[i] = __builtin_amdgcn_mfma_f32_16x16x32_bf16(a[i][1], b1, acc[i], 0,0,0);
        if (g*16 + l16 < M){
            #pragma unroll
            for (int i = 0; i < 4; ++i){
                sums[i][0] += fexp2(acc[i][0]);
                sums[i][1] += fexp2(acc[i][1]);
                sums[i][2] += fexp2(acc[i][2]);
                sums[i][3] += fexp2(acc[i][3]);
            }
        }
    };

    loadB(g0, p0a, p1a);
    loadB(g0 + 1, p0b, p1b);
    for (int g = g0; g < g1; g += 2){
        body(g, p0a, p1a);
        if (g + 2 < g1) loadB(g + 2, p0a, p1a);
        if (g + 1 < g1){
            body(g + 1, p0b, p1b);
            if (g + 3 < g1) loadB(g + 3, p0b, p1b);
        }
    }

    #pragma unroll
    for (int i = 0; i < 4; ++i){
        #pragma unroll
        for (int r = 0; r < 4; ++r){
            float v = sums[i][r];
            v += __shfl_xor(v, 1, 64);
            v += __shfl_xor(v, 2, 64);
            v += __shfl_xor(v, 4, 64);
            v += __shfl_xor(v, 8, 64);
            if (l16 == 0)
                atomicAdd(&s_out[row0 + i*16 + quad*4 + r], v);
        }
    }
}

// ------------- fused sumexp dispatch (interleaved phases) -------------------
__global__ __launch_bounds__(256) void k_sumexp(
    const unsigned short* __restrict__ Xb,  const unsigned short* __restrict__ hWb,
    const unsigned short* __restrict__ h0b, const unsigned short* __restrict__ e0b,
    const unsigned short* __restrict__ h1b, const unsigned short* __restrict__ e1b,
    float* __restrict__ sH, float* __restrict__ s0, float* __restrict__ s1)
{
    __shared__ __align__(16) unsigned short As[2*4096];
    __shared__ __align__(16) unsigned short Bs[2*4096];
    const int b = blockIdx.x;          // 2048 blocks: H,T1,T0,T1 repeating
    const int m4 = b & 3;
    if (m4 == 0){
        // head: K=1024, M=2002 (32 chunks), 8 col-splits x 4 chunks
        int id = b >> 2, rowb = id >> 3, split = id & 7;
        sumexp_lds<1024>(Xb, hWb, sH, 2002, rowb, split*4, split*4 + 4, As, Bs);
    } else if (m4 == 2){
        // tail0: K=256, M=8000 (125 chunks), 8 col-splits x 15/16 chunks
        int id = b >> 2, rowb = id >> 3, split = id & 7;
        int cb0 = split*15 + min(split, 5);
        int cb1 = cb0 + 15 + (split < 5 ? 1 : 0);
        sumexp_lds<256>(h0b, e0b, s0, 8000, rowb, cb0, cb1, As, Bs);
    } else {
        int wid = (b >> 1)*4 + (threadIdx.x >> 6);
        sumexp_stream64(h1b, e1b, s1, wid);
    }
}

// ---------------- combine: target logits + assemble log-probs ---------------
__global__ __launch_bounds__(256) void k_combine(
    const unsigned short* __restrict__ Xb,   // [4096][1024]
    const unsigned short* __restrict__ hWb,  // [2002][1024] (scaled)
    const unsigned short* __restrict__ h0b,  // [4096][256]
    const unsigned short* __restrict__ e0b,  // [8000][256] (scaled)
    const unsigned short* __restrict__ h1b,  // [4096][64]
    const unsigned short* __restrict__ e1b,  // [40257][64] (scaled)
    const float* __restrict__ sH, const float* __restrict__ s0,
    const float* __restrict__ s1,
    const int* __restrict__ targets, float* __restrict__ out)
{
    int w = threadIdx.x >> 6, lane = threadIdx.x & 63;
    int row = blockIdx.x*4 + w;
    int t = targets[row];
    int hidx = t < 2000 ? t : (t < 10000 ? 2000 : 2001);
    int rel0 = min(max(t - 2000, 0), 7999);
    int rel1 = min(max(t - 10000, 0), 40256);

    float dh = 0.f;
    {
        const uint4* xa = (const uint4*)(Xb  + row*1024  + lane*16);
        const uint4* wb = (const uint4*)(hWb + hidx*1024 + lane*16);
        #pragma unroll
        for (int p = 0; p < 2; ++p){
            uint4 xv = xa[p], wv = wb[p];
            dh += dotu(xv.x, wv.x) + dotu(xv.y, wv.y)
                + dotu(xv.z, wv.z) + dotu(xv.w, wv.w);
        }
    }
    float d0;
    {
        uint2 xv = *(const uint2*)(h0b + row*256  + lane*4);
        uint2 wv = *(const uint2*)(e0b + rel0*256 + lane*4);
        d0 = dotu(xv.x, wv.x) + dotu(xv.y, wv.y);
    }
    float d1 = b2f(h1b[row*64 + lane]) * b2f(e1b[rel1*64 + lane]);

    #pragma unroll
    for (int m = 1; m < 64; m <<= 1){
        dh += __shfl_xor(dh, m, 64);
        d0 += __shfl_xor(d0, m, 64);
        d1 += __shfl_xor(d1, m, 64);
    }
    if (lane == 0){
        float lp = dh - log2f(sH[row]);
        if (t >= 2000 && t < 10000) lp += d0 - log2f(s0[row]);
        if (t >= 10000)             lp += d1 - log2f(s1[row]);
        out[row] = LN2 * lp;
    }
}

__global__ void k_loss(const float* __restrict__ out, float* __restrict__ loss){
    __shared__ float red[1024];
    float s = 0.f;
    for (int i = threadIdx.x; i < 4096; i += 1024) s += out[i];
    red[threadIdx.x] = s;
    __syncthreads();
    for (int ofs = 512; ofs > 0; ofs >>= 1){
        if (threadIdx.x < ofs) red[threadIdx.x] += red[threadIdx.x + ofs];
        __syncthreads();
    }
    if (threadIdx.x == 0) loss[0] = -red[0] / 4096.f;
}

// ---------------- host launch ----------------
extern "C" void kernel_launch(void* const* d_in, const int* in_sizes, int n_in,
                              void* d_out, int out_size, void* d_ws, size_t ws_size,
                              hipStream_t stream) {
    const float* X      = (const float*)d_in[0];   // [4096][1024]
    const int*   tgt    = (const int*)  d_in[1];   // [4096]
    const float* headW  = (const float*)d_in[2];   // [2002][1024]
    const float* emb0   = (const float*)d_in[3];   // [8000][256]
    const float* lin0   = (const float*)d_in[4];   // [1024][256]
    const float* emb1   = (const float*)d_in[5];   // [40257][64]
    const float* lin1   = (const float*)d_in[6];   // [1024][64]
    float* out = (float*)d_out;                    // [4097]

    char* ws = (char*)d_ws;
    unsigned short* Xb  = (unsigned short*)(ws + 0);          // 8,388,608 B
    unsigned short* hWb = (unsigned short*)(ws + 8388608);    // 4,100,096 B
    unsigned short* e0b = (unsigned short*)(ws + 12488704);   // 4,096,000 B
    unsigned short* e1b = (unsigned short*)(ws + 16584704);   // 5,152,896 B
    unsigned short* l0T = (unsigned short*)(ws + 21737600);   //   524,288 B
    unsigned short* l1T = (unsigned short*)(ws + 22261888);   //   131,072 B
    unsigned short* h0b = (unsigned short*)(ws + 22392960);   // 2,097,152 B
    unsigned short* h1b = (unsigned short*)(ws + 24490112);   //   524,288 B
    float* sums         = (float*)(ws + 25014400);            // 3*4096 floats
    float* sH = sums, *s0 = sums + 4096, *s1 = sums + 8192;

    k_prep<<<2048, 256, 0, stream>>>(X, headW, emb0, emb1, lin0, lin1,
                                     Xb, hWb, e0b, e1b, l0T, l1T, sums);
    k_hgemm<<<dim3(64, 5), 256, 0, stream>>>(Xb, l0T, h0b, l1T, h1b);
    k_sumexp<<<2048, 256, 0, stream>>>(Xb, hWb, h0b, e0b, h1b, e1b, sH, s0, s1);
    k_combine<<<1024, 256, 0, stream>>>(Xb, hWb, h0b, e0b, h1b, e1b,
                                        sH, s0, s1, tgt, out);
    k_loss<<<1, 1024, 0, stream>>>(out, out + 4096);
}